// Round 11
// baseline (211.686 us; speedup 1.0000x reference)
//
#include <hip/hip_runtime.h>
#include <hip/hip_bf16.h>
#include <stdint.h>

// Problem dims
#define T_TOK 2048
#define HD    1024
#define NE    8
#define FD    1408
#define F2D   2816
#define HP    1056     // xbf row pitch (bf16)
#define OP    1056     // o row pitch (f32)

// GEMM tiling
#define BM 128
#define BK 32
#define MAXMT 40
#define MAXSLOTS 5120
#define FC1_NT 22      // FD/64
#define FC2_NT 16      // HD/64
#define FC1_NWG (FC1_NT * MAXMT)   // 880
#define FC2_NWG (FC2_NT * MAXMT)   // 640
#define FC1_CHUNK 110
#define FC2_CHUNK 80

typedef __attribute__((ext_vector_type(8))) short bf16x8;
typedef __attribute__((ext_vector_type(4))) float f32x4;
typedef __attribute__((ext_vector_type(2))) int i32x2;

__device__ __forceinline__ unsigned short f2bf(float f) {
  unsigned int u = __float_as_uint(f);
  u += 0x7FFFu + ((u >> 16) & 1u);   // RNE
  return (unsigned short)(u >> 16);
}

#define GLL16(gp, lp) __builtin_amdgcn_global_load_lds( \
    (const __attribute__((address_space(1))) void*)(gp), \
    (__attribute__((address_space(3))) void*)(lp), 16, 0, 0)

#define LDS_OFF(p) ((unsigned)(uintptr_t)(__attribute__((address_space(3))) const unsigned short*)(p))

// Transpose-read pair (verified r10): issue raw, wait at call site, unpack after.
__device__ __forceinline__ void tr_issue(unsigned a, i32x2& lo, i32x2& hi) {
  asm volatile("ds_read_b64_tr_b16 %0, %2\n\t"
               "ds_read_b64_tr_b16 %1, %2 offset:512"
               : "=&v"(lo), "=&v"(hi)
               : "v"(a)
               : "memory");
}
__device__ __forceinline__ bf16x8 tr_pack(i32x2 lo, i32x2 hi) {
  union { i32x2 v; short s[4]; } a, b;
  a.v = lo; b.v = hi;
  bf16x8 f;
  f[0] = a.s[0]; f[1] = a.s[1]; f[2] = a.s[2]; f[3] = a.s[3];
  f[4] = b.s[0]; f[5] = b.s[1]; f[6] = b.s[2]; f[7] = b.s[3];
  return f;
}

// ---------------------------------------------------------------------------
// Router: one wave per token. f32 logits, softmax, top-2, counts; emits x bf16
// (HP pitch). No weight prep anymore -- GEMMs read f32 weights directly.
// ---------------------------------------------------------------------------
__global__ __launch_bounds__(256) void k_router(
    const float* __restrict__ x, const float* __restrict__ rw,
    unsigned short* __restrict__ xbf, int* __restrict__ ctrl,
    int* __restrict__ tok_e, float* __restrict__ tok_p)
{
  const int lane = threadIdx.x & 63;
  const int t = blockIdx.x * 4 + (threadIdx.x >> 6);
  const float* xr = x + (size_t)t * HD;

  float part[8];
#pragma unroll
  for (int e = 0; e < 8; ++e) part[e] = 0.f;

#pragma unroll
  for (int i = 0; i < 16; ++i) {
    const int h = i * 64 + lane;
    const float xv = xr[h];
    xbf[(size_t)t * HP + h] = f2bf(xv);
    const float4* rwr = reinterpret_cast<const float4*>(rw + (size_t)h * 8);
    float4 a = rwr[0], bb = rwr[1];
    part[0] += xv * a.x; part[1] += xv * a.y; part[2] += xv * a.z; part[3] += xv * a.w;
    part[4] += xv * bb.x; part[5] += xv * bb.y; part[6] += xv * bb.z; part[7] += xv * bb.w;
  }
#pragma unroll
  for (int e = 0; e < 8; ++e) {
    float v = part[e];
#pragma unroll
    for (int d = 32; d; d >>= 1) v += __shfl_xor(v, d, 64);
    part[e] = v;
  }
  float m = part[0];
#pragma unroll
  for (int e = 1; e < 8; ++e) m = fmaxf(m, part[e]);
  float p[8], s = 0.f;
#pragma unroll
  for (int e = 0; e < 8; ++e) { p[e] = __expf(part[e] - m); s += p[e]; }
  const float inv = 1.f / s;
#pragma unroll
  for (int e = 0; e < 8; ++e) p[e] *= inv;

  int e0 = 0; float p0 = p[0];
#pragma unroll
  for (int e = 1; e < 8; ++e) if (p[e] > p0) { p0 = p[e]; e0 = e; }
  int e1 = -1; float p1 = -1.f;
#pragma unroll
  for (int e = 0; e < 8; ++e) if (e != e0 && p[e] > p1) { p1 = p[e]; e1 = e; }

  if (lane == 0) {
    tok_e[t * 2 + 0] = e0; tok_e[t * 2 + 1] = e1;
    tok_p[t * 2 + 0] = p0; tok_p[t * 2 + 1] = p1;
    atomicAdd(&ctrl[e0], 1);
    atomicAdd(&ctrl[e1], 1);
  }
}

// ---------------------------------------------------------------------------
// Offsets (unchanged).
// ---------------------------------------------------------------------------
__global__ __launch_bounds__(256) void k_offsets(
    int* __restrict__ ctrl, int* __restrict__ stok, float* __restrict__ sp,
    int* __restrict__ widmt1, int* __restrict__ widmt2)
{
  __shared__ int soff[8], scnt[8], sFirst[8], sNmt[8], sTake[8];
  __shared__ int sSpill;
  if (threadIdx.x == 0) {
    int o = 0, nm = 0, spill = 0;
    for (int e = 0; e < 8; ++e) {
      ctrl[16 + e] = o; soff[e] = o; scnt[e] = ctrl[e];
      const int n = ctrl[e];
      const int nmt = (n + BM - 1) / BM;
      sFirst[e] = nm; sNmt[e] = nmt; sTake[e] = nmt < 5 ? nmt : 5;
      if (nmt > 5) spill = 1;
      for (int j = 0; j < nmt; ++j) { ctrl[24 + nm] = e; ctrl[64 + nm] = o + j * BM; ++nm; }
      o += nmt * BM;
    }
    for (int i = nm; i < MAXMT; ++i) ctrl[24 + i] = -1;
    sSpill = spill;
  }
  __syncthreads();
  for (int i = threadIdx.x; i < FC1_NWG; i += 256) {
    const int e = i / FC1_CHUNK, r = i % FC1_CHUNK;
    const int j = r / FC1_NT, n = r % FC1_NT;
    widmt1[i] = (j < sTake[e]) ? (sFirst[e] + j) * 32 + n : -1;
  }
  for (int i = threadIdx.x; i < FC2_NWG; i += 256) {
    const int e = i / FC2_CHUNK, r = i % FC2_CHUNK;
    const int j = r / FC2_NT, n = r % FC2_NT;
    widmt2[i] = (j < sTake[e]) ? (sFirst[e] + j) * 32 + n : -1;
  }
  __syncthreads();
  if (sSpill && threadIdx.x == 0) {
    int cur = 0;
    for (int e = 0; e < 8; ++e)
      for (int j = 5; j < sNmt[e]; ++j)
        for (int n = 0; n < FC1_NT; ++n) {
          while (widmt1[cur] != -1) ++cur;
          widmt1[cur] = (sFirst[e] + j) * 32 + n;
        }
    cur = 0;
    for (int e = 0; e < 8; ++e)
      for (int j = 5; j < sNmt[e]; ++j)
        for (int n = 0; n < FC2_NT; ++n) {
          while (widmt2[cur] != -1) ++cur;
          widmt2[cur] = (sFirst[e] + j) * 32 + n;
        }
  }
  for (int e = 0; e < 8; ++e) {
    const int n = scnt[e], o = soff[e];
    const int padEnd = (n + BM - 1) / BM * BM;
    for (int j = n + (int)threadIdx.x; j < padEnd; j += 256) {
      stok[o + j] = 0; sp[o + j] = 0.f;
    }
  }
}

// ---------------------------------------------------------------------------
// Scatter (unchanged).
// ---------------------------------------------------------------------------
__global__ __launch_bounds__(256) void k_scatter(
    int* __restrict__ ctrl, const int* __restrict__ tok_e,
    const float* __restrict__ tok_p, int* __restrict__ stok,
    float* __restrict__ sp, int* __restrict__ tslot)
{
  const int t = blockIdx.x * 256 + threadIdx.x;
#pragma unroll
  for (int k = 0; k < 2; ++k) {
    const int e = tok_e[t * 2 + k];
    const float pp = tok_p[t * 2 + k];
    const int pos = atomicAdd(&ctrl[8 + e], 1);
    const int slot = ctrl[16 + e] + pos;
    stok[slot] = t; sp[slot] = pp;
    tslot[t * 2 + k] = slot;
  }
}

// ---------------------------------------------------------------------------
// fc1: y = X[slots] @ w1[e] (gate|up), fused silu(y1)*y2*p -> bf16 g.
// B read DIRECTLY from f32 w1 (contiguous 32 B/lane), cvt in regs, ds_write
// into the same subtiled slot GLL16 filled in r10 (tr-reads unchanged).
// r6-proven reg-staging pipeline: per-iter VMEM queue [A(t), B(t+1), A(t+1)],
// steady wait vmcnt(2).
// ---------------------------------------------------------------------------
__global__ __launch_bounds__(256) void k_fc1(
    const unsigned short* __restrict__ xbf,   // [T][HP] bf16
    const float* __restrict__ w1,             // [E][H][2F] f32 (native input)
    const int* __restrict__ ctrl,
    const int* __restrict__ stok,
    const float* __restrict__ sp,
    const int* __restrict__ widmt1,
    unsigned short* __restrict__ g)           // [MAXSLOTS][F] bf16
{
  const int bid = blockIdx.x;
  const int wid = (bid & 7) * FC1_CHUNK + (bid >> 3);
  const int packed = widmt1[wid];
  if (packed < 0) return;
  const int mt = packed >> 5;
  const int e = ctrl[24 + mt];
  const int rowbase = ctrl[64 + mt];
  const int n0 = (packed & 31) * 64;

  __shared__ unsigned short sA[3][BM * BK];   // 8 KB each
  __shared__ unsigned short sB1[3][64 * BK];  // 4 KB each (subtiled)
  __shared__ unsigned short sB2[3][64 * BK];

  const int tid = threadIdx.x;
  const int lane = tid & 63;
  const int wave = tid >> 6;
  const int wm = wave >> 1, wn = wave & 1;

  // A staging (proven): pre-swizzled source chunk.
  const int schunk = (lane & 3) ^ ((lane >> 3) & 3);
  const unsigned short* aSrc[2];
#pragma unroll
  for (int t4 = 0; t4 < 2; ++t4) {
    const int row = (t4 * 4 + wave) * 16 + (lane >> 2);
    const int tok = stok[rowbase + row];
    aSrc[t4] = xbf + (size_t)tok * HP + schunk * 8;
  }

  // B source decode (same as r10's verified kdec/ndec), but f32.
  const int kdec = wave * 8 + ((lane >> 5) << 2) + ((lane >> 1) & 3);
  const int ndec = ((lane >> 3) & 3) * 16 + (lane & 1) * 8;
  const float* b1SrcF = w1 + ((size_t)e * HD + kdec) * F2D + n0 + ndec;
  const float* b2SrcF = b1SrcF + FD;

  // A fragment LDS offsets (XOR-swizzled, conflict-free)
  const int c = lane >> 4;
  int aoff[4];
#pragma unroll
  for (int m = 0; m < 4; ++m) {
    const int row = wm * 64 + m * 16 + (lane & 15);
    aoff[m] = row * 32 + ((c ^ ((row >> 1) & 3)) << 3);
  }
  const unsigned trlane = (lane & 15) * 8 + (lane >> 4) * 1024;
  unsigned trb[2];
#pragma unroll
  for (int n = 0; n < 2; ++n) trb[n] = trlane + (wn * 2 + n) * 128;
  const unsigned b1base = LDS_OFF(&sB1[0][0]);
  const unsigned b2base = LDS_OFF(&sB2[0][0]);

  const f32x4 zero = {0.f, 0.f, 0.f, 0.f};
  f32x4 acc1[4][2], acc2[4][2];
#pragma unroll
  for (int m = 0; m < 4; ++m)
#pragma unroll
    for (int n = 0; n < 2; ++n) { acc1[m][n] = zero; acc2[m][n] = zero; }

  float b1r[8], b2r[8];
  auto BLOAD = [&](int kt) {
    const float* p1 = b1SrcF + (size_t)kt * BK * F2D;
    const float* p2 = b2SrcF + (size_t)kt * BK * F2D;
    *(float4*)&b1r[0] = *(const float4*)p1;
    *(float4*)&b1r[4] = *(const float4*)(p1 + 4);
    *(float4*)&b2r[0] = *(const float4*)p2;
    *(float4*)&b2r[4] = *(const float4*)(p2 + 4);
  };
  auto BWRITE = [&](int buf) {
    bf16x8 v1, v2;
#pragma unroll
    for (int j = 0; j < 8; ++j) {
      v1[j] = (short)f2bf(b1r[j]);
      v2[j] = (short)f2bf(b2r[j]);
    }
    *(bf16x8*)&sB1[buf][wave * 512 + lane * 8] = v1;
    *(bf16x8*)&sB2[buf][wave * 512 + lane * 8] = v2;
  };
  auto ASTAGE = [&](int buf, int kt) {
#pragma unroll
    for (int t4 = 0; t4 < 2; ++t4)
      GLL16(aSrc[t4] + (size_t)kt * BK, &sA[buf][(t4 * 4 + wave) * 512]);
  };

  const int NSTEP = HD / BK;   // 32
  // prologue (issue order pinned: B-loads then A-GLL)
  BLOAD(0);
  __builtin_amdgcn_sched_barrier(0);
  ASTAGE(0, 0);
  __builtin_amdgcn_sched_barrier(0);
  asm volatile("s_waitcnt vmcnt(2)" ::: "memory");   // B0 done, A0 in flight
  BWRITE(0);
  BLOAD(1);
  __builtin_amdgcn_sched_barrier(0);
  ASTAGE(1, 1);
  __builtin_amdgcn_sched_barrier(0);
  asm volatile("s_waitcnt lgkmcnt(0)" ::: "memory"); // BWRITE(0) drained

  int bsel = 0;
  for (int t = 0; t < NSTEP; ++t) {
    if (t < NSTEP - 1) { asm volatile("s_waitcnt vmcnt(2)" ::: "memory"); }
    else               { asm volatile("s_waitcnt vmcnt(0)" ::: "memory"); }
    __builtin_amdgcn_s_barrier();
    __builtin_amdgcn_sched_barrier(0);
    int bnext = bsel + 1; if (bnext >= 3) bnext -= 3;
    int bn2 = bsel + 2; if (bn2 >= 3) bn2 -= 3;
    if (t + 1 < NSTEP) BWRITE(bnext);
    if (t + 2 < NSTEP) {
      BLOAD(t + 2);
      __builtin_amdgcn_sched_barrier(0);
      ASTAGE(bn2, t + 2);
      __builtin_amdgcn_sched_barrier(0);
    }
    bf16x8 af[4];
#pragma unroll
    for (int m = 0; m < 4; ++m)
      af[m] = *(const bf16x8*)&sA[bsel][aoff[m]];
    i32x2 q1lo[2], q1hi[2], q2lo[2], q2hi[2];
#pragma unroll
    for (int n = 0; n < 2; ++n) {
      tr_issue(b1base + bsel * 4096 + trb[n], q1lo[n], q1hi[n]);
      tr_issue(b2base + bsel * 4096 + trb[n], q2lo[n], q2hi[n]);
    }
    asm volatile("s_waitcnt lgkmcnt(0)" ::: "memory");
    __builtin_amdgcn_sched_barrier(0);
    bf16x8 b1f[2], b2f[2];
#pragma unroll
    for (int n = 0; n < 2; ++n) {
      b1f[n] = tr_pack(q1lo[n], q1hi[n]);
      b2f[n] = tr_pack(q2lo[n], q2hi[n]);
    }
    __builtin_amdgcn_s_setprio(1);
#pragma unroll
    for (int m = 0; m < 4; ++m)
#pragma unroll
      for (int n = 0; n < 2; ++n) {
        acc1[m][n] = __builtin_amdgcn_mfma_f32_16x16x32_bf16(af[m], b1f[n], acc1[m][n], 0, 0, 0);
        acc2[m][n] = __builtin_amdgcn_mfma_f32_16x16x32_bf16(af[m], b2f[n], acc2[m][n], 0, 0, 0);
      }
    __builtin_amdgcn_s_setprio(0);
    bsel = bnext;
  }

  float prv[4][4];
#pragma unroll
  for (int m = 0; m < 4; ++m)
#pragma unroll
    for (int r = 0; r < 4; ++r)
      prv[m][r] = sp[rowbase + wm * 64 + m * 16 + (lane >> 4) * 4 + r];

#pragma unroll
  for (int m = 0; m < 4; ++m) {
    const int rb = rowbase + wm * 64 + m * 16 + (lane >> 4) * 4;
#pragma unroll
    for (int n = 0; n < 2; ++n) {
      const int col = n0 + wn * 32 + n * 16 + (lane & 15);
#pragma unroll
      for (int r = 0; r < 4; ++r) {
        const float y1 = acc1[m][n][r];
        const float y2 = acc2[m][n][r];
        const float gv = y1 / (1.f + __expf(-y1)) * y2 * prv[m][r];
        g[(size_t)(rb + r) * FD + col] = f2bf(gv);
      }
    }
  }
}

// ---------------------------------------------------------------------------
// fc2: o[slot] = g[slot] @ w2[e] -- B directly from f32 w2 (native [F][1024]).
// ---------------------------------------------------------------------------
__global__ __launch_bounds__(256) void k_fc2(
    const unsigned short* __restrict__ g,     // [MAXSLOTS][F] bf16
    const float* __restrict__ w2,             // [E][F][H] f32 (native input)
    const int* __restrict__ ctrl,
    const int* __restrict__ widmt2,
    float* __restrict__ o)                    // [MAXSLOTS][OP] f32
{
  const int bid = blockIdx.x;
  const int wid = (bid & 7) * FC2_CHUNK + (bid >> 3);
  const int packed = widmt2[wid];
  if (packed < 0) return;
  const int mt = packed >> 5;
  const int e = ctrl[24 + mt];
  const int rowbase = ctrl[64 + mt];
  const int n0 = (packed & 31) * 64;

  __shared__ unsigned short sA[3][BM * BK];   // 8 KB each
  __shared__ unsigned short sB[3][64 * BK];   // 4 KB each (subtiled)

  const int tid = threadIdx.x;
  const int lane = tid & 63;
  const int wave = tid >> 6;
  const int wm = wave >> 1, wn = wave & 1;

  const int schunk = (lane & 3) ^ ((lane >> 3) & 3);
  const unsigned short* aSrc[2];
#pragma unroll
  for (int t4 = 0; t4 < 2; ++t4) {
    const int row = (t4 * 4 + wave) * 16 + (lane >> 2);
    aSrc[t4] = g + (size_t)(rowbase + row) * FD + schunk * 8;
  }

  const int kdec = wave * 8 + ((lane >> 5) << 2) + ((lane >> 1) & 3);
  const int ndec = ((lane >> 3) & 3) * 16 + (lane & 1) * 8;
  const float* bSrcF = w2 + ((size_t)e * FD + kdec) * HD + n0 + ndec;

  const int c = lane >> 4;
  int aoff[4];
#pragma unroll
  for (int m = 0; m < 4; ++m) {
    const int row = wm * 64 + m * 16 + (lane & 15);
    aoff[m] = row * 32 + ((c ^ ((row >> 1) & 3)) << 3);
  }
  const unsigned trlane = (lane & 15) * 8 + (lane >> 4) * 1024;
  unsigned trb[2];
#pragma unroll
  for (int n = 0; n < 2; ++n) trb[n] = trlane + (wn * 2 + n) * 128;
  const unsigned bbase = LDS_OFF(&sB[0][0]);

  const f32x4 zero = {0.f, 0.f, 0.f, 0.f};
  f32x4 acc[4][2];
#pragma unroll
  for (int m = 0; m < 4; ++m)
#pragma unroll
    for (int n = 0; n < 2; ++n) acc[m][n] = zero;

  float br[8];
  auto BLOAD = [&](int kt) {
    const float* p = bSrcF + (size_t)kt * BK * HD;
    *(float4*)&br[0] = *(const float4*)p;
    *(float4*)&br[4] = *(const float4*)(p + 4);
  };
  auto BWRITE = [&](int buf) {
    bf16x8 v;
#pragma unroll
    for (int j = 0; j < 8; ++j) v[j] = (short)f2bf(br[j]);
    *(bf16x8*)&sB[buf][wave * 512 + lane * 8] = v;
  };
  auto ASTAGE = [&](int buf, int kt) {
#pragma unroll
    for (int t4 = 0; t4 < 2; ++t4)
      GLL16(aSrc[t4] + (size_t)kt * BK, &sA[buf][(t4 * 4 + wave) * 512]);
  };

  const int NSTEP = FD / BK;   // 44
  BLOAD(0);
  __builtin_amdgcn_sched_barrier(0);
  ASTAGE(0, 0);
  __builtin_amdgcn_sched_barrier(0);
  asm volatile("s_waitcnt vmcnt(2)" ::: "memory");   // B0 done, A0 in flight
  BWRITE(0);
  BLOAD(1);
  __builtin_amdgcn_sched_barrier(0);
  ASTAGE(1, 1);
  __builtin_amdgcn_sched_barrier(0);
  asm volatile("s_waitcnt lgkmcnt(0)" ::: "memory");

  int bsel = 0;
  for (int t = 0; t < NSTEP; ++t) {
    if (t < NSTEP - 1) { asm volatile("s_waitcnt vmcnt(2)" ::: "memory"); }
    else               { asm volatile("s_waitcnt vmcnt(0)" ::: "memory"); }
    __builtin_amdgcn_s_barrier();
    __builtin_amdgcn_sched_barrier(0);
    int bnext = bsel + 1; if (bnext >= 3) bnext -= 3;
    int bn2 = bsel + 2; if (bn2 >= 3) bn2 -= 3;
    if (t + 1 < NSTEP) BWRITE(bnext);
    if (t + 2 < NSTEP) {
      BLOAD(t + 2);
      __builtin_amdgcn_sched_barrier(0);
      ASTAGE(bn2, t + 2);
      __builtin_amdgcn_sched_barrier(0);
    }
    bf16x8 af[4];
#pragma unroll
    for (int m = 0; m < 4; ++m)
      af[m] = *(const bf16x8*)&sA[bsel][aoff[m]];
    i32x2 qlo[2], qhi[2];
#pragma unroll
    for (int n = 0; n < 2; ++n)
      tr_issue(bbase + bsel * 4096 + trb[n], qlo[n], qhi[n]);
    asm volatile("s_waitcnt lgkmcnt(0)" ::: "memory");
    __builtin_amdgcn_sched_barrier(0);
    bf16x8 bf[2];
#pragma unroll
    for (int n = 0; n < 2; ++n)
      bf[n] = tr_pack(qlo[n], qhi[n]);
    __builtin_amdgcn_s_setprio(1);
#pragma unroll
    for (int m = 0; m < 4; ++m)
#pragma unroll
      for (int n = 0; n < 2; ++n)
        acc[m][n] = __builtin_amdgcn_mfma_f32_16x16x32_bf16(af[m], bf[n], acc[m][n], 0, 0, 0);
    __builtin_amdgcn_s_setprio(0);
    bsel = bnext;
  }

#pragma unroll
  for (int m = 0; m < 4; ++m) {
    const int rb = rowbase + wm * 64 + m * 16 + (lane >> 4) * 4;
#pragma unroll
    for (int n = 0; n < 2; ++n) {
      const int col = n0 + wn * 32 + n * 16 + (lane & 15);
#pragma unroll
      for (int r = 0; r < 4; ++r)
        o[(size_t)(rb + r) * OP + col] = acc[m][n][r];
    }
  }
}

// ---------------------------------------------------------------------------
// Combine (unchanged).
// ---------------------------------------------------------------------------
__global__ __launch_bounds__(256) void k_combine(
    const float* __restrict__ o, const int* __restrict__ tslot,
    float* __restrict__ out)
{
  const int t = blockIdx.x;
  const int c4 = threadIdx.x;
  const int sA = tslot[t * 2], sB = tslot[t * 2 + 1];
  const float4 a = reinterpret_cast<const float4*>(o + (size_t)sA * OP)[c4];
  const float4 b = reinterpret_cast<const float4*>(o + (size_t)sB * OP)[c4];
  float4 r;
  r.x = a.x + b.x; r.y = a.y + b.y; r.z = a.z + b.z; r.w = a.w + b.w;
  reinterpret_cast<float4*>(out)[(size_t)t * 256 + c4] = r;
}

// ---------------------------------------------------------------------------
extern "C" void kernel_launch(void* const* d_in, const int* in_sizes, int n_in,
                              void* d_out, int out_size, void* d_ws, size_t ws_size,
                              hipStream_t stream)
{
  const float* x  = (const float*)d_in[0];   // [2048,1,1024]
  const float* rw = (const float*)d_in[1];   // [1024,8]
  const float* w1 = (const float*)d_in[2];   // [8,1024,2816]
  const float* w2 = (const float*)d_in[3];   // [8,1408,1024]
  float* out = (float*)d_out;
  char* ws = (char*)d_ws;

  // ws layout (bytes)
  int*   ctrl   = (int*)(ws + 0);
  int*   tok_e  = (int*)(ws + 1024);
  float* tok_p  = (float*)(ws + 17408);
  int*   stok   = (int*)(ws + 33792);
  float* sp     = (float*)(ws + 54272);
  int*   tslot  = (int*)(ws + 74752);
  int*   widmt1 = (int*)(ws + 91136);
  int*   widmt2 = (int*)(ws + 94656);
  unsigned short* xbf = (unsigned short*)(ws + 97280);   // [T][HP]     4.33 MB
  unsigned short* g   = (unsigned short*)(ws + 4422656); // [SLOTS][F]  14.5 MB
  float*          o   = (float*)(ws + 18840576);         // [SLOTS][OP] 21.6 MB

  hipMemsetAsync(ws, 0, 1024, stream);

  k_router<<<T_TOK / 4, 256, 0, stream>>>(x, rw, xbf, ctrl, tok_e, tok_p);
  k_offsets<<<1, 256, 0, stream>>>(ctrl, stok, sp, widmt1, widmt2);
  k_scatter<<<T_TOK / 256, 256, 0, stream>>>(ctrl, tok_e, tok_p, stok, sp, tslot);
  k_fc1<<<FC1_NWG, 256, 0, stream>>>(xbf, w1, ctrl, stok, sp, widmt1, g);
  k_fc2<<<FC2_NWG, 256, 0, stream>>>(g, w2, ctrl, widmt2, o);
  k_combine<<<T_TOK, 256, 0, stream>>>(o, tslot, out);
}

// Round 12
// 197.982 us; speedup vs baseline: 1.0692x; 1.0692x over previous
//
#include <hip/hip_runtime.h>
#include <hip/hip_bf16.h>
#include <stdint.h>

// Problem dims
#define T_TOK 2048
#define HD    1024
#define NE    8
#define FD    1408
#define F2D   2816
#define HP    1056     // xbf row pitch (bf16)
#define OP    1056     // o row pitch (f32)

// GEMM tiling
#define BM 128
#define BK 32
#define MAXMT 40
#define MAXSLOTS 5120
#define FC1_NT 22      // FD/64
#define FC2_NT 16      // HD/64
#define FC1_NWG (FC1_NT * MAXMT)   // 880
#define FC2_NWG (FC2_NT * MAXMT)   // 640
#define FC1_CHUNK 110
#define FC2_CHUNK 80

typedef __attribute__((ext_vector_type(8))) short bf16x8;
typedef __attribute__((ext_vector_type(4))) float f32x4;
typedef __attribute__((ext_vector_type(2))) int i32x2;

__device__ __forceinline__ unsigned short f2bf(float f) {
  unsigned int u = __float_as_uint(f);
  u += 0x7FFFu + ((u >> 16) & 1u);   // RNE
  return (unsigned short)(u >> 16);
}

#define GLL16(gp, lp) __builtin_amdgcn_global_load_lds( \
    (const __attribute__((address_space(1))) void*)(gp), \
    (__attribute__((address_space(3))) void*)(lp), 16, 0, 0)

#define LDS_OFF(p) ((unsigned)(uintptr_t)(__attribute__((address_space(3))) const unsigned short*)(p))

// Transpose-read pair (verified r10): issue raw, wait at call site, unpack after.
__device__ __forceinline__ void tr_issue(unsigned a, i32x2& lo, i32x2& hi) {
  asm volatile("ds_read_b64_tr_b16 %0, %2\n\t"
               "ds_read_b64_tr_b16 %1, %2 offset:512"
               : "=&v"(lo), "=&v"(hi)
               : "v"(a)
               : "memory");
}
__device__ __forceinline__ bf16x8 tr_pack(i32x2 lo, i32x2 hi) {
  union { i32x2 v; short s[4]; } a, b;
  a.v = lo; b.v = hi;
  bf16x8 f;
  f[0] = a.s[0]; f[1] = a.s[1]; f[2] = a.s[2]; f[3] = a.s[3];
  f[4] = b.s[0]; f[5] = b.s[1]; f[6] = b.s[2]; f[7] = b.s[3];
  return f;
}

// ---------------------------------------------------------------------------
// Router: one wave per token. f32 logits, softmax, top-2, counts; emits x bf16.
// ---------------------------------------------------------------------------
__global__ __launch_bounds__(256) void k_router(
    const float* __restrict__ x, const float* __restrict__ rw,
    unsigned short* __restrict__ xbf, int* __restrict__ ctrl,
    int* __restrict__ tok_e, float* __restrict__ tok_p)
{
  const int lane = threadIdx.x & 63;
  const int t = blockIdx.x * 4 + (threadIdx.x >> 6);
  const float* xr = x + (size_t)t * HD;

  float part[8];
#pragma unroll
  for (int e = 0; e < 8; ++e) part[e] = 0.f;

#pragma unroll
  for (int i = 0; i < 16; ++i) {
    const int h = i * 64 + lane;
    const float xv = xr[h];
    xbf[(size_t)t * HP + h] = f2bf(xv);
    const float4* rwr = reinterpret_cast<const float4*>(rw + (size_t)h * 8);
    float4 a = rwr[0], bb = rwr[1];
    part[0] += xv * a.x; part[1] += xv * a.y; part[2] += xv * a.z; part[3] += xv * a.w;
    part[4] += xv * bb.x; part[5] += xv * bb.y; part[6] += xv * bb.z; part[7] += xv * bb.w;
  }
#pragma unroll
  for (int e = 0; e < 8; ++e) {
    float v = part[e];
#pragma unroll
    for (int d = 32; d; d >>= 1) v += __shfl_xor(v, d, 64);
    part[e] = v;
  }
  float m = part[0];
#pragma unroll
  for (int e = 1; e < 8; ++e) m = fmaxf(m, part[e]);
  float p[8], s = 0.f;
#pragma unroll
  for (int e = 0; e < 8; ++e) { p[e] = __expf(part[e] - m); s += p[e]; }
  const float inv = 1.f / s;
#pragma unroll
  for (int e = 0; e < 8; ++e) p[e] *= inv;

  int e0 = 0; float p0 = p[0];
#pragma unroll
  for (int e = 1; e < 8; ++e) if (p[e] > p0) { p0 = p[e]; e0 = e; }
  int e1 = -1; float p1 = -1.f;
#pragma unroll
  for (int e = 0; e < 8; ++e) if (e != e0 && p[e] > p1) { p1 = p[e]; e1 = e; }

  if (lane == 0) {
    tok_e[t * 2 + 0] = e0; tok_e[t * 2 + 1] = e1;
    tok_p[t * 2 + 0] = p0; tok_p[t * 2 + 1] = p1;
    atomicAdd(&ctrl[e0], 1);
    atomicAdd(&ctrl[e1], 1);
  }
}

// ---------------------------------------------------------------------------
// Offsets (unchanged).
// ---------------------------------------------------------------------------
__global__ __launch_bounds__(256) void k_offsets(
    int* __restrict__ ctrl, int* __restrict__ stok, float* __restrict__ sp,
    int* __restrict__ widmt1, int* __restrict__ widmt2)
{
  __shared__ int soff[8], scnt[8], sFirst[8], sNmt[8], sTake[8];
  __shared__ int sSpill;
  if (threadIdx.x == 0) {
    int o = 0, nm = 0, spill = 0;
    for (int e = 0; e < 8; ++e) {
      ctrl[16 + e] = o; soff[e] = o; scnt[e] = ctrl[e];
      const int n = ctrl[e];
      const int nmt = (n + BM - 1) / BM;
      sFirst[e] = nm; sNmt[e] = nmt; sTake[e] = nmt < 5 ? nmt : 5;
      if (nmt > 5) spill = 1;
      for (int j = 0; j < nmt; ++j) { ctrl[24 + nm] = e; ctrl[64 + nm] = o + j * BM; ++nm; }
      o += nmt * BM;
    }
    for (int i = nm; i < MAXMT; ++i) ctrl[24 + i] = -1;
    sSpill = spill;
  }
  __syncthreads();
  for (int i = threadIdx.x; i < FC1_NWG; i += 256) {
    const int e = i / FC1_CHUNK, r = i % FC1_CHUNK;
    const int j = r / FC1_NT, n = r % FC1_NT;
    widmt1[i] = (j < sTake[e]) ? (sFirst[e] + j) * 32 + n : -1;
  }
  for (int i = threadIdx.x; i < FC2_NWG; i += 256) {
    const int e = i / FC2_CHUNK, r = i % FC2_CHUNK;
    const int j = r / FC2_NT, n = r % FC2_NT;
    widmt2[i] = (j < sTake[e]) ? (sFirst[e] + j) * 32 + n : -1;
  }
  __syncthreads();
  if (sSpill && threadIdx.x == 0) {
    int cur = 0;
    for (int e = 0; e < 8; ++e)
      for (int j = 5; j < sNmt[e]; ++j)
        for (int n = 0; n < FC1_NT; ++n) {
          while (widmt1[cur] != -1) ++cur;
          widmt1[cur] = (sFirst[e] + j) * 32 + n;
        }
    cur = 0;
    for (int e = 0; e < 8; ++e)
      for (int j = 5; j < sNmt[e]; ++j)
        for (int n = 0; n < FC2_NT; ++n) {
          while (widmt2[cur] != -1) ++cur;
          widmt2[cur] = (sFirst[e] + j) * 32 + n;
        }
  }
  for (int e = 0; e < 8; ++e) {
    const int n = scnt[e], o = soff[e];
    const int padEnd = (n + BM - 1) / BM * BM;
    for (int j = n + (int)threadIdx.x; j < padEnd; j += 256) {
      stok[o + j] = 0; sp[o + j] = 0.f;
    }
  }
}

// ---------------------------------------------------------------------------
// Scatter (unchanged).
// ---------------------------------------------------------------------------
__global__ __launch_bounds__(256) void k_scatter(
    int* __restrict__ ctrl, const int* __restrict__ tok_e,
    const float* __restrict__ tok_p, int* __restrict__ stok,
    float* __restrict__ sp, int* __restrict__ tslot)
{
  const int t = blockIdx.x * 256 + threadIdx.x;
#pragma unroll
  for (int k = 0; k < 2; ++k) {
    const int e = tok_e[t * 2 + k];
    const float pp = tok_p[t * 2 + k];
    const int pos = atomicAdd(&ctrl[8 + e], 1);
    const int slot = ctrl[16 + e] + pos;
    stok[slot] = t; sp[slot] = pp;
    tslot[t * 2 + k] = slot;
  }
}

// ---------------------------------------------------------------------------
// fc1: y = X[slots] @ w1[e] (gate|up), fused silu(y1)*y2*p -> bf16 g.
// B direct from f32 w1 with DEPTH-2 reg-bank staging (banks r0/r1, static via
// unroll-2). Per-iter VMEM queue [B(t+3):4, A(t+2):2]; steady wait vmcnt(6).
// ---------------------------------------------------------------------------
__global__ __launch_bounds__(256) void k_fc1(
    const unsigned short* __restrict__ xbf,   // [T][HP] bf16
    const float* __restrict__ w1,             // [E][H][2F] f32 (native input)
    const int* __restrict__ ctrl,
    const int* __restrict__ stok,
    const float* __restrict__ sp,
    const int* __restrict__ widmt1,
    unsigned short* __restrict__ g)           // [MAXSLOTS][F] bf16
{
  const int bid = blockIdx.x;
  const int wid = (bid & 7) * FC1_CHUNK + (bid >> 3);
  const int packed = widmt1[wid];
  if (packed < 0) return;
  const int mt = packed >> 5;
  const int e = ctrl[24 + mt];
  const int rowbase = ctrl[64 + mt];
  const int n0 = (packed & 31) * 64;

  __shared__ unsigned short sA[3][BM * BK];   // 8 KB each
  __shared__ unsigned short sB1[3][64 * BK];  // 4 KB each (subtiled)
  __shared__ unsigned short sB2[3][64 * BK];

  const int tid = threadIdx.x;
  const int lane = tid & 63;
  const int wave = tid >> 6;
  const int wm = wave >> 1, wn = wave & 1;

  const int schunk = (lane & 3) ^ ((lane >> 3) & 3);
  const unsigned short* aSrc[2];
#pragma unroll
  for (int t4 = 0; t4 < 2; ++t4) {
    const int row = (t4 * 4 + wave) * 16 + (lane >> 2);
    const int tok = stok[rowbase + row];
    aSrc[t4] = xbf + (size_t)tok * HP + schunk * 8;
  }

  const int kdec = wave * 8 + ((lane >> 5) << 2) + ((lane >> 1) & 3);
  const int ndec = ((lane >> 3) & 3) * 16 + (lane & 1) * 8;
  const float* b1SrcF = w1 + ((size_t)e * HD + kdec) * F2D + n0 + ndec;
  const float* b2SrcF = b1SrcF + FD;

  const int c = lane >> 4;
  int aoff[4];
#pragma unroll
  for (int m = 0; m < 4; ++m) {
    const int row = wm * 64 + m * 16 + (lane & 15);
    aoff[m] = row * 32 + ((c ^ ((row >> 1) & 3)) << 3);
  }
  const unsigned trlane = (lane & 15) * 8 + (lane >> 4) * 1024;
  unsigned trb[2];
#pragma unroll
  for (int n = 0; n < 2; ++n) trb[n] = trlane + (wn * 2 + n) * 128;
  const unsigned b1base = LDS_OFF(&sB1[0][0]);
  const unsigned b2base = LDS_OFF(&sB2[0][0]);

  const f32x4 zero = {0.f, 0.f, 0.f, 0.f};
  f32x4 acc1[4][2], acc2[4][2];
#pragma unroll
  for (int m = 0; m < 4; ++m)
#pragma unroll
    for (int n = 0; n < 2; ++n) { acc1[m][n] = zero; acc2[m][n] = zero; }

  // two named register banks per stream (static indexing)
  float b1r0[8], b2r0[8], b1r1[8], b2r1[8];

#define FC1_BLOAD(KT, R1, R2) do {                                  \
    const float* _p1 = b1SrcF + (size_t)(KT) * BK * F2D;            \
    const float* _p2 = b2SrcF + (size_t)(KT) * BK * F2D;            \
    *(float4*)&R1[0] = *(const float4*)_p1;                         \
    *(float4*)&R1[4] = *(const float4*)(_p1 + 4);                   \
    *(float4*)&R2[0] = *(const float4*)_p2;                         \
    *(float4*)&R2[4] = *(const float4*)(_p2 + 4);                   \
  } while (0)

#define FC1_BWRITE(BUF, R1, R2) do {                                \
    bf16x8 _v1, _v2;                                                \
    for (int _j = 0; _j < 8; ++_j) {                                \
      _v1[_j] = (short)f2bf(R1[_j]);                                \
      _v2[_j] = (short)f2bf(R2[_j]);                                \
    }                                                               \
    *(bf16x8*)&sB1[BUF][wave * 512 + lane * 8] = _v1;               \
    *(bf16x8*)&sB2[BUF][wave * 512 + lane * 8] = _v2;               \
  } while (0)

#define FC1_ASTAGE(BUF, KT) do {                                    \
    for (int _t4 = 0; _t4 < 2; ++_t4)                               \
      GLL16(aSrc[_t4] + (size_t)(KT) * BK, &sA[BUF][(_t4 * 4 + wave) * 512]); \
  } while (0)

  const int NSTEP = HD / BK;   // 32
  // ---- prologue: lands steady queue [B1:4, A0:2, B2:4, A1:2] ----
  FC1_BLOAD(0, b1r0, b2r0);
  __builtin_amdgcn_sched_barrier(0);
  asm volatile("s_waitcnt vmcnt(0)" ::: "memory");
  FC1_BWRITE(0, b1r0, b2r0);
  __builtin_amdgcn_sched_barrier(0);
  FC1_BLOAD(1, b1r1, b2r1);
  __builtin_amdgcn_sched_barrier(0);
  FC1_ASTAGE(0, 0);
  __builtin_amdgcn_sched_barrier(0);
  FC1_BLOAD(2, b1r0, b2r0);
  __builtin_amdgcn_sched_barrier(0);
  FC1_ASTAGE(1, 1);
  __builtin_amdgcn_sched_barrier(0);
  asm volatile("s_waitcnt lgkmcnt(0)" ::: "memory");   // BWRITE(0) drained

#define FC1_STEP(T, R1, R2) do {                                             \
    const int _t = (T);                                                      \
    if (_t < NSTEP - 2)      { asm volatile("s_waitcnt vmcnt(6)" ::: "memory"); } \
    else if (_t == NSTEP - 2){ asm volatile("s_waitcnt vmcnt(2)" ::: "memory"); } \
    else                     { asm volatile("s_waitcnt vmcnt(0)" ::: "memory"); } \
    __builtin_amdgcn_s_barrier();                                            \
    __builtin_amdgcn_sched_barrier(0);                                       \
    int _bnext = bsel + 1; if (_bnext >= 3) _bnext -= 3;                     \
    int _bn2 = bsel + 2; if (_bn2 >= 3) _bn2 -= 3;                           \
    if (_t + 1 < NSTEP) FC1_BWRITE(_bnext, R1, R2);                          \
    __builtin_amdgcn_sched_barrier(0);                                       \
    if (_t + 3 < NSTEP) FC1_BLOAD(_t + 3, R1, R2);                           \
    __builtin_amdgcn_sched_barrier(0);                                       \
    if (_t + 2 < NSTEP) FC1_ASTAGE(_bn2, _t + 2);                            \
    __builtin_amdgcn_sched_barrier(0);                                       \
    bf16x8 _af[4];                                                           \
    for (int _m = 0; _m < 4; ++_m)                                           \
      _af[_m] = *(const bf16x8*)&sA[bsel][aoff[_m]];                         \
    i32x2 _q1lo[2], _q1hi[2], _q2lo[2], _q2hi[2];                            \
    for (int _n = 0; _n < 2; ++_n) {                                         \
      tr_issue(b1base + bsel * 4096 + trb[_n], _q1lo[_n], _q1hi[_n]);        \
      tr_issue(b2base + bsel * 4096 + trb[_n], _q2lo[_n], _q2hi[_n]);        \
    }                                                                        \
    asm volatile("s_waitcnt lgkmcnt(0)" ::: "memory");                       \
    __builtin_amdgcn_sched_barrier(0);                                       \
    bf16x8 _b1f[2], _b2f[2];                                                 \
    for (int _n = 0; _n < 2; ++_n) {                                         \
      _b1f[_n] = tr_pack(_q1lo[_n], _q1hi[_n]);                              \
      _b2f[_n] = tr_pack(_q2lo[_n], _q2hi[_n]);                              \
    }                                                                        \
    __builtin_amdgcn_s_setprio(1);                                           \
    for (int _m = 0; _m < 4; ++_m)                                           \
      for (int _n = 0; _n < 2; ++_n) {                                       \
        acc1[_m][_n] = __builtin_amdgcn_mfma_f32_16x16x32_bf16(_af[_m], _b1f[_n], acc1[_m][_n], 0, 0, 0); \
        acc2[_m][_n] = __builtin_amdgcn_mfma_f32_16x16x32_bf16(_af[_m], _b2f[_n], acc2[_m][_n], 0, 0, 0); \
      }                                                                      \
    __builtin_amdgcn_s_setprio(0);                                           \
  } while (0)

  int bsel = 0;
  for (int tt = 0; tt < NSTEP; tt += 2) {
    FC1_STEP(tt, b1r1, b2r1);       // even t: bank1
    bsel = bsel + 1 == 3 ? 0 : bsel + 1;
    FC1_STEP(tt + 1, b1r0, b2r0);   // odd t: bank0
    bsel = bsel + 1 == 3 ? 0 : bsel + 1;
  }

  float prv[4][4];
#pragma unroll
  for (int m = 0; m < 4; ++m)
#pragma unroll
    for (int r = 0; r < 4; ++r)
      prv[m][r] = sp[rowbase + wm * 64 + m * 16 + (lane >> 4) * 4 + r];

#pragma unroll
  for (int m = 0; m < 4; ++m) {
    const int rb = rowbase + wm * 64 + m * 16 + (lane >> 4) * 4;
#pragma unroll
    for (int n = 0; n < 2; ++n) {
      const int col = n0 + wn * 32 + n * 16 + (lane & 15);
#pragma unroll
      for (int r = 0; r < 4; ++r) {
        const float y1 = acc1[m][n][r];
        const float y2 = acc2[m][n][r];
        const float gv = y1 / (1.f + __expf(-y1)) * y2 * prv[m][r];
        g[(size_t)(rb + r) * FD + col] = f2bf(gv);
      }
    }
  }
}

// ---------------------------------------------------------------------------
// fc2: o[slot] = g[slot] @ w2[e] -- depth-2 B reg-banks, same scheme.
// Per-iter VMEM queue [B(t+3):2, A(t+2):2]; steady wait vmcnt(4).
// ---------------------------------------------------------------------------
__global__ __launch_bounds__(256) void k_fc2(
    const unsigned short* __restrict__ g,     // [MAXSLOTS][F] bf16
    const float* __restrict__ w2,             // [E][F][H] f32 (native input)
    const int* __restrict__ ctrl,
    const int* __restrict__ widmt2,
    float* __restrict__ o)                    // [MAXSLOTS][OP] f32
{
  const int bid = blockIdx.x;
  const int wid = (bid & 7) * FC2_CHUNK + (bid >> 3);
  const int packed = widmt2[wid];
  if (packed < 0) return;
  const int mt = packed >> 5;
  const int e = ctrl[24 + mt];
  const int rowbase = ctrl[64 + mt];
  const int n0 = (packed & 31) * 64;

  __shared__ unsigned short sA[3][BM * BK];   // 8 KB each
  __shared__ unsigned short sB[3][64 * BK];   // 4 KB each (subtiled)

  const int tid = threadIdx.x;
  const int lane = tid & 63;
  const int wave = tid >> 6;
  const int wm = wave >> 1, wn = wave & 1;

  const int schunk = (lane & 3) ^ ((lane >> 3) & 3);
  const unsigned short* aSrc[2];
#pragma unroll
  for (int t4 = 0; t4 < 2; ++t4) {
    const int row = (t4 * 4 + wave) * 16 + (lane >> 2);
    aSrc[t4] = g + (size_t)(rowbase + row) * FD + schunk * 8;
  }

  const int kdec = wave * 8 + ((lane >> 5) << 2) + ((lane >> 1) & 3);
  const int ndec = ((lane >> 3) & 3) * 16 + (lane & 1) * 8;
  const float* bSrcF = w2 + ((size_t)e * FD + kdec) * HD + n0 + ndec;

  const int c = lane >> 4;
  int aoff[4];
#pragma unroll
  for (int m = 0; m < 4; ++m) {
    const int row = wm * 64 + m * 16 + (lane & 15);
    aoff[m] = row * 32 + ((c ^ ((row >> 1) & 3)) << 3);
  }
  const unsigned trlane = (lane & 15) * 8 + (lane >> 4) * 1024;
  unsigned trb[2];
#pragma unroll
  for (int n = 0; n < 2; ++n) trb[n] = trlane + (wn * 2 + n) * 128;
  const unsigned bbase = LDS_OFF(&sB[0][0]);

  const f32x4 zero = {0.f, 0.f, 0.f, 0.f};
  f32x4 acc[4][2];
#pragma unroll
  for (int m = 0; m < 4; ++m)
#pragma unroll
    for (int n = 0; n < 2; ++n) acc[m][n] = zero;

  float br0[8], br1[8];

#define FC2_BLOAD(KT, R) do {                                       \
    const float* _p = bSrcF + (size_t)(KT) * BK * HD;               \
    *(float4*)&R[0] = *(const float4*)_p;                           \
    *(float4*)&R[4] = *(const float4*)(_p + 4);                     \
  } while (0)

#define FC2_BWRITE(BUF, R) do {                                     \
    bf16x8 _v;                                                      \
    for (int _j = 0; _j < 8; ++_j) _v[_j] = (short)f2bf(R[_j]);     \
    *(bf16x8*)&sB[BUF][wave * 512 + lane * 8] = _v;                 \
  } while (0)

#define FC2_ASTAGE(BUF, KT) do {                                    \
    for (int _t4 = 0; _t4 < 2; ++_t4)                               \
      GLL16(aSrc[_t4] + (size_t)(KT) * BK, &sA[BUF][(_t4 * 4 + wave) * 512]); \
  } while (0)

  const int NSTEP = FD / BK;   // 44
  // ---- prologue: lands steady queue [B1:2, A0:2, B2:2, A1:2] ----
  FC2_BLOAD(0, br0);
  __builtin_amdgcn_sched_barrier(0);
  asm volatile("s_waitcnt vmcnt(0)" ::: "memory");
  FC2_BWRITE(0, br0);
  __builtin_amdgcn_sched_barrier(0);
  FC2_BLOAD(1, br1);
  __builtin_amdgcn_sched_barrier(0);
  FC2_ASTAGE(0, 0);
  __builtin_amdgcn_sched_barrier(0);
  FC2_BLOAD(2, br0);
  __builtin_amdgcn_sched_barrier(0);
  FC2_ASTAGE(1, 1);
  __builtin_amdgcn_sched_barrier(0);
  asm volatile("s_waitcnt lgkmcnt(0)" ::: "memory");

#define FC2_STEP(T, R) do {                                                  \
    const int _t = (T);                                                      \
    if (_t < NSTEP - 2)      { asm volatile("s_waitcnt vmcnt(4)" ::: "memory"); } \
    else if (_t == NSTEP - 2){ asm volatile("s_waitcnt vmcnt(2)" ::: "memory"); } \
    else                     { asm volatile("s_waitcnt vmcnt(0)" ::: "memory"); } \
    __builtin_amdgcn_s_barrier();                                            \
    __builtin_amdgcn_sched_barrier(0);                                       \
    int _bnext = bsel + 1; if (_bnext >= 3) _bnext -= 3;                     \
    int _bn2 = bsel + 2; if (_bn2 >= 3) _bn2 -= 3;                           \
    if (_t + 1 < NSTEP) FC2_BWRITE(_bnext, R);                               \
    __builtin_amdgcn_sched_barrier(0);                                       \
    if (_t + 3 < NSTEP) FC2_BLOAD(_t + 3, R);                                \
    __builtin_amdgcn_sched_barrier(0);                                       \
    if (_t + 2 < NSTEP) FC2_ASTAGE(_bn2, _t + 2);                            \
    __builtin_amdgcn_sched_barrier(0);                                       \
    bf16x8 _af[4];                                                           \
    for (int _m = 0; _m < 4; ++_m)                                           \
      _af[_m] = *(const bf16x8*)&sA[bsel][aoff[_m]];                         \
    i32x2 _qlo[2], _qhi[2];                                                  \
    for (int _n = 0; _n < 2; ++_n)                                           \
      tr_issue(bbase + bsel * 4096 + trb[_n], _qlo[_n], _qhi[_n]);           \
    asm volatile("s_waitcnt lgkmcnt(0)" ::: "memory");                       \
    __builtin_amdgcn_sched_barrier(0);                                       \
    bf16x8 _bf[2];                                                           \
    for (int _n = 0; _n < 2; ++_n) _bf[_n] = tr_pack(_qlo[_n], _qhi[_n]);    \
    __builtin_amdgcn_s_setprio(1);                                           \
    for (int _m = 0; _m < 4; ++_m)                                           \
      for (int _n = 0; _n < 2; ++_n)                                         \
        acc[_m][_n] = __builtin_amdgcn_mfma_f32_16x16x32_bf16(_af[_m], _bf[_n], acc[_m][_n], 0, 0, 0); \
    __builtin_amdgcn_s_setprio(0);                                           \
  } while (0)

  int bsel = 0;
  for (int tt = 0; tt < NSTEP; tt += 2) {
    FC2_STEP(tt, br1);       // even t: bank1
    bsel = bsel + 1 == 3 ? 0 : bsel + 1;
    FC2_STEP(tt + 1, br0);   // odd t: bank0
    bsel = bsel + 1 == 3 ? 0 : bsel + 1;
  }

#pragma unroll
  for (int m = 0; m < 4; ++m) {
    const int rb = rowbase + wm * 64 + m * 16 + (lane >> 4) * 4;
#pragma unroll
    for (int n = 0; n < 2; ++n) {
      const int col = n0 + wn * 32 + n * 16 + (lane & 15);
#pragma unroll
      for (int r = 0; r < 4; ++r)
        o[(size_t)(rb + r) * OP + col] = acc[m][n][r];
    }
  }
}

// ---------------------------------------------------------------------------
// Combine (unchanged).
// ---------------------------------------------------------------------------
__global__ __launch_bounds__(256) void k_combine(
    const float* __restrict__ o, const int* __restrict__ tslot,
    float* __restrict__ out)
{
  const int t = blockIdx.x;
  const int c4 = threadIdx.x;
  const int sA = tslot[t * 2], sB = tslot[t * 2 + 1];
  const float4 a = reinterpret_cast<const float4*>(o + (size_t)sA * OP)[c4];
  const float4 b = reinterpret_cast<const float4*>(o + (size_t)sB * OP)[c4];
  float4 r;
  r.x = a.x + b.x; r.y = a.y + b.y; r.z = a.z + b.z; r.w = a.w + b.w;
  reinterpret_cast<float4*>(out)[(size_t)t * 256 + c4] = r;
}

// ---------------------------------------------------------------------------
extern "C" void kernel_launch(void* const* d_in, const int* in_sizes, int n_in,
                              void* d_out, int out_size, void* d_ws, size_t ws_size,
                              hipStream_t stream)
{
  const float* x  = (const float*)d_in[0];   // [2048,1,1024]
  const float* rw = (const float*)d_in[1];   // [1024,8]
  const float* w1 = (const float*)d_in[2];   // [8,1024,2816]
  const float* w2 = (const float*)d_in[3];   // [8,1408,1024]
  float* out = (float*)d_out;
  char* ws = (char*)d_ws;

  // ws layout (bytes)
  int*   ctrl   = (int*)(ws + 0);
  int*   tok_e  = (int*)(ws + 1024);
  float* tok_p  = (float*)(ws + 17408);
  int*   stok   = (int*)(ws + 33792);
  float* sp     = (float*)(ws + 54272);
  int*   tslot  = (int*)(ws + 74752);
  int*   widmt1 = (int*)(ws + 91136);
  int*   widmt2 = (int*)(ws + 94656);
  unsigned short* xbf = (unsigned short*)(ws + 97280);   // [T][HP]     4.33 MB
  unsigned short* g   = (unsigned short*)(ws + 4422656); // [SLOTS][F]  14.5 MB
  float*          o   = (float*)(ws + 18840576);         // [SLOTS][OP] 21.6 MB

  hipMemsetAsync(ws, 0, 1024, stream);

  k_router<<<T_TOK / 4, 256, 0, stream>>>(x, rw, xbf, ctrl, tok_e, tok_p);
  k_offsets<<<1, 256, 0, stream>>>(ctrl, stok, sp, widmt1, widmt2);
  k_scatter<<<T_TOK / 256, 256, 0, stream>>>(ctrl, tok_e, tok_p, stok, sp, tslot);
  k_fc1<<<FC1_NWG, 256, 0, stream>>>(xbf, w1, ctrl, stok, sp, widmt1, g);
  k_fc2<<<FC2_NWG, 256, 0, stream>>>(g, w2, ctrl, widmt2, o);
  k_combine<<<T_TOK, 256, 0, stream>>>(o, tslot, out);
}

// Round 13
// 170.742 us; speedup vs baseline: 1.2398x; 1.1595x over previous
//
#include <hip/hip_runtime.h>
#include <hip/hip_bf16.h>
#include <stdint.h>

// Problem dims
#define T_TOK 2048
#define HD    1024
#define NE    8
#define FD    1408
#define F2D   2816
#define HP    1056     // xbf row pitch (bf16)
#define OP    1056     // o row pitch (f32)

// GEMM tiling
#define BM 128
#define BK 32
#define MAXMT 40
#define MAXSLOTS 5120
#define FC1_NT 22      // FD/64
#define FC2_NT 16      // HD/64
#define FC1_NWG (FC1_NT * MAXMT)   // 880
#define FC2_NWG (FC2_NT * MAXMT)   // 640
#define FC1_CHUNK 110
#define FC2_CHUNK 80

typedef __attribute__((ext_vector_type(8))) short bf16x8;
typedef __attribute__((ext_vector_type(4))) float f32x4;
typedef __attribute__((ext_vector_type(2))) int i32x2;

__device__ __forceinline__ unsigned short f2bf(float f) {
  unsigned int u = __float_as_uint(f);
  u += 0x7FFFu + ((u >> 16) & 1u);   // RNE
  return (unsigned short)(u >> 16);
}

#define GLL16(gp, lp) __builtin_amdgcn_global_load_lds( \
    (const __attribute__((address_space(1))) void*)(gp), \
    (__attribute__((address_space(3))) void*)(lp), 16, 0, 0)

#define LDS_OFF(p) ((unsigned)(uintptr_t)(__attribute__((address_space(3))) const unsigned short*)(p))

// Transpose-read pair (verified r10): issue raw, wait at call site, unpack after.
__device__ __forceinline__ void tr_issue(unsigned a, i32x2& lo, i32x2& hi) {
  asm volatile("ds_read_b64_tr_b16 %0, %2\n\t"
               "ds_read_b64_tr_b16 %1, %2 offset:512"
               : "=&v"(lo), "=&v"(hi)
               : "v"(a)
               : "memory");
}
__device__ __forceinline__ bf16x8 tr_pack(i32x2 lo, i32x2 hi) {
  union { i32x2 v; short s[4]; } a, b;
  a.v = lo; b.v = hi;
  bf16x8 f;
  f[0] = a.s[0]; f[1] = a.s[1]; f[2] = a.s[2]; f[3] = a.s[3];
  f[4] = b.s[0]; f[5] = b.s[1]; f[6] = b.s[2]; f[7] = b.s[3];
  return f;
}

// ---------------------------------------------------------------------------
// Router: one wave per token. f32 logits, softmax, top-2, counts; emits x bf16.
// ---------------------------------------------------------------------------
__global__ __launch_bounds__(256) void k_router(
    const float* __restrict__ x, const float* __restrict__ rw,
    unsigned short* __restrict__ xbf, int* __restrict__ ctrl,
    int* __restrict__ tok_e, float* __restrict__ tok_p)
{
  const int lane = threadIdx.x & 63;
  const int t = blockIdx.x * 4 + (threadIdx.x >> 6);
  const float* xr = x + (size_t)t * HD;

  float part[8];
#pragma unroll
  for (int e = 0; e < 8; ++e) part[e] = 0.f;

#pragma unroll
  for (int i = 0; i < 16; ++i) {
    const int h = i * 64 + lane;
    const float xv = xr[h];
    xbf[(size_t)t * HP + h] = f2bf(xv);
    const float4* rwr = reinterpret_cast<const float4*>(rw + (size_t)h * 8);
    float4 a = rwr[0], bb = rwr[1];
    part[0] += xv * a.x; part[1] += xv * a.y; part[2] += xv * a.z; part[3] += xv * a.w;
    part[4] += xv * bb.x; part[5] += xv * bb.y; part[6] += xv * bb.z; part[7] += xv * bb.w;
  }
#pragma unroll
  for (int e = 0; e < 8; ++e) {
    float v = part[e];
#pragma unroll
    for (int d = 32; d; d >>= 1) v += __shfl_xor(v, d, 64);
    part[e] = v;
  }
  float m = part[0];
#pragma unroll
  for (int e = 1; e < 8; ++e) m = fmaxf(m, part[e]);
  float p[8], s = 0.f;
#pragma unroll
  for (int e = 0; e < 8; ++e) { p[e] = __expf(part[e] - m); s += p[e]; }
  const float inv = 1.f / s;
#pragma unroll
  for (int e = 0; e < 8; ++e) p[e] *= inv;

  int e0 = 0; float p0 = p[0];
#pragma unroll
  for (int e = 1; e < 8; ++e) if (p[e] > p0) { p0 = p[e]; e0 = e; }
  int e1 = -1; float p1 = -1.f;
#pragma unroll
  for (int e = 0; e < 8; ++e) if (e != e0 && p[e] > p1) { p1 = p[e]; e1 = e; }

  if (lane == 0) {
    tok_e[t * 2 + 0] = e0; tok_e[t * 2 + 1] = e1;
    tok_p[t * 2 + 0] = p0; tok_p[t * 2 + 1] = p1;
    atomicAdd(&ctrl[e0], 1);
    atomicAdd(&ctrl[e1], 1);
  }
}

// ---------------------------------------------------------------------------
// Offsets + scatter (merged, single block): scan, mtile tables, widmt
// schedules, zero-pad slots, and token scatter via LDS cursors.
// ctrl: [0..7]=cnt [16..23]=off [24..63]=mtE [64..103]=mtB
// ---------------------------------------------------------------------------
__global__ __launch_bounds__(256) void k_offsets(
    int* __restrict__ ctrl, const int* __restrict__ tok_e,
    const float* __restrict__ tok_p, int* __restrict__ stok,
    float* __restrict__ sp, int* __restrict__ tslot,
    int* __restrict__ widmt1, int* __restrict__ widmt2)
{
  __shared__ int soff[8], scnt[8], sFirst[8], sNmt[8], sTake[8], sCur[8];
  __shared__ int sSpill;
  if (threadIdx.x == 0) {
    int o = 0, nm = 0, spill = 0;
    for (int e = 0; e < 8; ++e) {
      ctrl[16 + e] = o; soff[e] = o; scnt[e] = ctrl[e]; sCur[e] = 0;
      const int n = ctrl[e];
      const int nmt = (n + BM - 1) / BM;
      sFirst[e] = nm; sNmt[e] = nmt; sTake[e] = nmt < 5 ? nmt : 5;
      if (nmt > 5) spill = 1;
      for (int j = 0; j < nmt; ++j) { ctrl[24 + nm] = e; ctrl[64 + nm] = o + j * BM; ++nm; }
      o += nmt * BM;
    }
    for (int i = nm; i < MAXMT; ++i) ctrl[24 + i] = -1;
    sSpill = spill;
  }
  __syncthreads();
  for (int i = threadIdx.x; i < FC1_NWG; i += 256) {
    const int e = i / FC1_CHUNK, r = i % FC1_CHUNK;
    const int j = r / FC1_NT, n = r % FC1_NT;
    widmt1[i] = (j < sTake[e]) ? (sFirst[e] + j) * 32 + n : -1;
  }
  for (int i = threadIdx.x; i < FC2_NWG; i += 256) {
    const int e = i / FC2_CHUNK, r = i % FC2_CHUNK;
    const int j = r / FC2_NT, n = r % FC2_NT;
    widmt2[i] = (j < sTake[e]) ? (sFirst[e] + j) * 32 + n : -1;
  }
  __syncthreads();
  if (sSpill && threadIdx.x == 0) {
    int cur = 0;
    for (int e = 0; e < 8; ++e)
      for (int j = 5; j < sNmt[e]; ++j)
        for (int n = 0; n < FC1_NT; ++n) {
          while (widmt1[cur] != -1) ++cur;
          widmt1[cur] = (sFirst[e] + j) * 32 + n;
        }
    cur = 0;
    for (int e = 0; e < 8; ++e)
      for (int j = 5; j < sNmt[e]; ++j)
        for (int n = 0; n < FC2_NT; ++n) {
          while (widmt2[cur] != -1) ++cur;
          widmt2[cur] = (sFirst[e] + j) * 32 + n;
        }
  }
  // zero-pad slots beyond each expert's count
  for (int e = 0; e < 8; ++e) {
    const int n = scnt[e], o = soff[e];
    const int padEnd = (n + BM - 1) / BM * BM;
    for (int j = n + (int)threadIdx.x; j < padEnd; j += 256) {
      stok[o + j] = 0; sp[o + j] = 0.f;
    }
  }
  // scatter all tokens (LDS cursors; any within-expert order is valid)
  for (int i = threadIdx.x; i < T_TOK; i += 256) {
#pragma unroll
    for (int k = 0; k < 2; ++k) {
      const int e = tok_e[i * 2 + k];
      const int pos = atomicAdd(&sCur[e], 1);
      const int slot = soff[e] + pos;
      stok[slot] = i; sp[slot] = tok_p[i * 2 + k];
      tslot[i * 2 + k] = slot;
    }
  }
}

// ---------------------------------------------------------------------------
// fc1: y = X[slots] @ w1[e] (gate|up), fused silu(y1)*y2*p -> bf16 g.
// Depth-2 B reg-banks (r12 schedule) + v_cvt_pk_bf16_f32 BWRITE +
// split-wait compute (MFMA n0 overlaps n1 tr-reads).
// ---------------------------------------------------------------------------
__global__ __launch_bounds__(256) void k_fc1(
    const unsigned short* __restrict__ xbf,   // [T][HP] bf16
    const float* __restrict__ w1,             // [E][H][2F] f32 (native input)
    const int* __restrict__ ctrl,
    const int* __restrict__ stok,
    const float* __restrict__ sp,
    const int* __restrict__ widmt1,
    unsigned short* __restrict__ g)           // [MAXSLOTS][F] bf16
{
  const int bid = blockIdx.x;
  const int wid = (bid & 7) * FC1_CHUNK + (bid >> 3);
  const int packed = widmt1[wid];
  if (packed < 0) return;
  const int mt = packed >> 5;
  const int e = ctrl[24 + mt];
  const int rowbase = ctrl[64 + mt];
  const int n0 = (packed & 31) * 64;

  __shared__ unsigned short sA[3][BM * BK];   // 8 KB each
  __shared__ unsigned short sB1[3][64 * BK];  // 4 KB each (subtiled)
  __shared__ unsigned short sB2[3][64 * BK];

  const int tid = threadIdx.x;
  const int lane = tid & 63;
  const int wave = tid >> 6;
  const int wm = wave >> 1, wn = wave & 1;

  const int schunk = (lane & 3) ^ ((lane >> 3) & 3);
  const unsigned short* aSrc[2];
#pragma unroll
  for (int t4 = 0; t4 < 2; ++t4) {
    const int row = (t4 * 4 + wave) * 16 + (lane >> 2);
    const int tok = stok[rowbase + row];
    aSrc[t4] = xbf + (size_t)tok * HP + schunk * 8;
  }

  const int kdec = wave * 8 + ((lane >> 5) << 2) + ((lane >> 1) & 3);
  const int ndec = ((lane >> 3) & 3) * 16 + (lane & 1) * 8;
  const float* b1SrcF = w1 + ((size_t)e * HD + kdec) * F2D + n0 + ndec;
  const float* b2SrcF = b1SrcF + FD;

  const int c = lane >> 4;
  int aoff[4];
#pragma unroll
  for (int m = 0; m < 4; ++m) {
    const int row = wm * 64 + m * 16 + (lane & 15);
    aoff[m] = row * 32 + ((c ^ ((row >> 1) & 3)) << 3);
  }
  const unsigned trlane = (lane & 15) * 8 + (lane >> 4) * 1024;
  unsigned trb[2];
#pragma unroll
  for (int n = 0; n < 2; ++n) trb[n] = trlane + (wn * 2 + n) * 128;
  const unsigned b1base = LDS_OFF(&sB1[0][0]);
  const unsigned b2base = LDS_OFF(&sB2[0][0]);

  const f32x4 zero = {0.f, 0.f, 0.f, 0.f};
  f32x4 acc1[4][2], acc2[4][2];
#pragma unroll
  for (int m = 0; m < 4; ++m)
#pragma unroll
    for (int n = 0; n < 2; ++n) { acc1[m][n] = zero; acc2[m][n] = zero; }

  // two named register banks per stream (static indexing)
  float b1r0[8], b2r0[8], b1r1[8], b2r1[8];

#define FC1_BLOAD(KT, R1, R2) do {                                  \
    const float* _p1 = b1SrcF + (size_t)(KT) * BK * F2D;            \
    const float* _p2 = b2SrcF + (size_t)(KT) * BK * F2D;            \
    *(float4*)&R1[0] = *(const float4*)_p1;                         \
    *(float4*)&R1[4] = *(const float4*)(_p1 + 4);                   \
    *(float4*)&R2[0] = *(const float4*)_p2;                         \
    *(float4*)&R2[4] = *(const float4*)(_p2 + 4);                   \
  } while (0)

#define FC1_BWRITE(BUF, R1, R2) do {                                \
    unsigned _a0,_a1,_a2,_a3,_c0,_c1,_c2,_c3;                       \
    asm("v_cvt_pk_bf16_f32 %0, %1, %2" : "=v"(_a0) : "v"(R1[0]), "v"(R1[1])); \
    asm("v_cvt_pk_bf16_f32 %0, %1, %2" : "=v"(_a1) : "v"(R1[2]), "v"(R1[3])); \
    asm("v_cvt_pk_bf16_f32 %0, %1, %2" : "=v"(_a2) : "v"(R1[4]), "v"(R1[5])); \
    asm("v_cvt_pk_bf16_f32 %0, %1, %2" : "=v"(_a3) : "v"(R1[6]), "v"(R1[7])); \
    asm("v_cvt_pk_bf16_f32 %0, %1, %2" : "=v"(_c0) : "v"(R2[0]), "v"(R2[1])); \
    asm("v_cvt_pk_bf16_f32 %0, %1, %2" : "=v"(_c1) : "v"(R2[2]), "v"(R2[3])); \
    asm("v_cvt_pk_bf16_f32 %0, %1, %2" : "=v"(_c2) : "v"(R2[4]), "v"(R2[5])); \
    asm("v_cvt_pk_bf16_f32 %0, %1, %2" : "=v"(_c3) : "v"(R2[6]), "v"(R2[7])); \
    uint4 _u1 = make_uint4(_a0,_a1,_a2,_a3);                        \
    uint4 _u2 = make_uint4(_c0,_c1,_c2,_c3);                        \
    *(uint4*)&sB1[BUF][wave * 512 + lane * 8] = _u1;                \
    *(uint4*)&sB2[BUF][wave * 512 + lane * 8] = _u2;                \
  } while (0)

#define FC1_ASTAGE(BUF, KT) do {                                    \
    for (int _t4 = 0; _t4 < 2; ++_t4)                               \
      GLL16(aSrc[_t4] + (size_t)(KT) * BK, &sA[BUF][(_t4 * 4 + wave) * 512]); \
  } while (0)

  const int NSTEP = HD / BK;   // 32
  // ---- prologue: lands steady queue [B1:4, A0:2, B2:4, A1:2] ----
  FC1_BLOAD(0, b1r0, b2r0);
  __builtin_amdgcn_sched_barrier(0);
  asm volatile("s_waitcnt vmcnt(0)" ::: "memory");
  FC1_BWRITE(0, b1r0, b2r0);
  __builtin_amdgcn_sched_barrier(0);
  FC1_BLOAD(1, b1r1, b2r1);
  __builtin_amdgcn_sched_barrier(0);
  FC1_ASTAGE(0, 0);
  __builtin_amdgcn_sched_barrier(0);
  FC1_BLOAD(2, b1r0, b2r0);
  __builtin_amdgcn_sched_barrier(0);
  FC1_ASTAGE(1, 1);
  __builtin_amdgcn_sched_barrier(0);
  asm volatile("s_waitcnt lgkmcnt(0)" ::: "memory");   // BWRITE(0) drained

#define FC1_STEP(T, R1, R2) do {                                             \
    const int _t = (T);                                                      \
    if (_t < NSTEP - 2)      { asm volatile("s_waitcnt vmcnt(6)" ::: "memory"); } \
    else if (_t == NSTEP - 2){ asm volatile("s_waitcnt vmcnt(2)" ::: "memory"); } \
    else                     { asm volatile("s_waitcnt vmcnt(0)" ::: "memory"); } \
    __builtin_amdgcn_s_barrier();                                            \
    __builtin_amdgcn_sched_barrier(0);                                       \
    int _bnext = bsel + 1; if (_bnext >= 3) _bnext -= 3;                     \
    int _bn2 = bsel + 2; if (_bn2 >= 3) _bn2 -= 3;                           \
    if (_t + 1 < NSTEP) FC1_BWRITE(_bnext, R1, R2);                          \
    __builtin_amdgcn_sched_barrier(0);                                       \
    if (_t + 3 < NSTEP) FC1_BLOAD(_t + 3, R1, R2);                           \
    __builtin_amdgcn_sched_barrier(0);                                       \
    if (_t + 2 < NSTEP) FC1_ASTAGE(_bn2, _t + 2);                            \
    __builtin_amdgcn_sched_barrier(0);                                       \
    bf16x8 _af[4];                                                           \
    for (int _m = 0; _m < 4; ++_m)                                           \
      _af[_m] = *(const bf16x8*)&sA[bsel][aoff[_m]];                         \
    __builtin_amdgcn_sched_barrier(0);                                       \
    i32x2 _q1lo[2], _q1hi[2], _q2lo[2], _q2hi[2];                            \
    tr_issue(b1base + bsel * 4096 + trb[0], _q1lo[0], _q1hi[0]);             \
    tr_issue(b2base + bsel * 4096 + trb[0], _q2lo[0], _q2hi[0]);             \
    __builtin_amdgcn_sched_barrier(0);                                       \
    tr_issue(b1base + bsel * 4096 + trb[1], _q1lo[1], _q1hi[1]);             \
    tr_issue(b2base + bsel * 4096 + trb[1], _q2lo[1], _q2hi[1]);             \
    asm volatile("s_waitcnt lgkmcnt(4)" ::: "memory");                       \
    __builtin_amdgcn_sched_barrier(0);                                       \
    bf16x8 _b1f0 = tr_pack(_q1lo[0], _q1hi[0]);                              \
    bf16x8 _b2f0 = tr_pack(_q2lo[0], _q2hi[0]);                              \
    __builtin_amdgcn_s_setprio(1);                                           \
    for (int _m = 0; _m < 4; ++_m) {                                         \
      acc1[_m][0] = __builtin_amdgcn_mfma_f32_16x16x32_bf16(_af[_m], _b1f0, acc1[_m][0], 0, 0, 0); \
      acc2[_m][0] = __builtin_amdgcn_mfma_f32_16x16x32_bf16(_af[_m], _b2f0, acc2[_m][0], 0, 0, 0); \
    }                                                                        \
    __builtin_amdgcn_s_setprio(0);                                           \
    asm volatile("s_waitcnt lgkmcnt(0)" ::: "memory");                       \
    __builtin_amdgcn_sched_barrier(0);                                       \
    bf16x8 _b1f1 = tr_pack(_q1lo[1], _q1hi[1]);                              \
    bf16x8 _b2f1 = tr_pack(_q2lo[1], _q2hi[1]);                              \
    __builtin_amdgcn_s_setprio(1);                                           \
    for (int _m = 0; _m < 4; ++_m) {                                         \
      acc1[_m][1] = __builtin_amdgcn_mfma_f32_16x16x32_bf16(_af[_m], _b1f1, acc1[_m][1], 0, 0, 0); \
      acc2[_m][1] = __builtin_amdgcn_mfma_f32_16x16x32_bf16(_af[_m], _b2f1, acc2[_m][1], 0, 0, 0); \
    }                                                                        \
    __builtin_amdgcn_s_setprio(0);                                           \
  } while (0)

  int bsel = 0;
  for (int tt = 0; tt < NSTEP; tt += 2) {
    FC1_STEP(tt, b1r1, b2r1);       // even t: bank1
    bsel = bsel + 1 == 3 ? 0 : bsel + 1;
    FC1_STEP(tt + 1, b1r0, b2r0);   // odd t: bank0
    bsel = bsel + 1 == 3 ? 0 : bsel + 1;
  }

  float prv[4][4];
#pragma unroll
  for (int m = 0; m < 4; ++m)
#pragma unroll
    for (int r = 0; r < 4; ++r)
      prv[m][r] = sp[rowbase + wm * 64 + m * 16 + (lane >> 4) * 4 + r];

#pragma unroll
  for (int m = 0; m < 4; ++m) {
    const int rb = rowbase + wm * 64 + m * 16 + (lane >> 4) * 4;
#pragma unroll
    for (int n = 0; n < 2; ++n) {
      const int col = n0 + wn * 32 + n * 16 + (lane & 15);
#pragma unroll
      for (int r = 0; r < 4; ++r) {
        const float y1 = acc1[m][n][r];
        const float y2 = acc2[m][n][r];
        const float gv = y1 / (1.f + __expf(-y1)) * y2 * prv[m][r];
        g[(size_t)(rb + r) * FD + col] = f2bf(gv);
      }
    }
  }
}

// ---------------------------------------------------------------------------
// fc2: o[slot] = g[slot] @ w2[e] -- depth-2 B reg-banks + cvt_pk BWRITE +
// split-wait compute. Per-iter VMEM queue [B(t+3):2, A(t+2):2]; vmcnt(4).
// ---------------------------------------------------------------------------
__global__ __launch_bounds__(256) void k_fc2(
    const unsigned short* __restrict__ g,     // [MAXSLOTS][F] bf16
    const float* __restrict__ w2,             // [E][F][H] f32 (native input)
    const int* __restrict__ ctrl,
    const int* __restrict__ widmt2,
    float* __restrict__ o)                    // [MAXSLOTS][OP] f32
{
  const int bid = blockIdx.x;
  const int wid = (bid & 7) * FC2_CHUNK + (bid >> 3);
  const int packed = widmt2[wid];
  if (packed < 0) return;
  const int mt = packed >> 5;
  const int e = ctrl[24 + mt];
  const int rowbase = ctrl[64 + mt];
  const int n0 = (packed & 31) * 64;

  __shared__ unsigned short sA[3][BM * BK];   // 8 KB each
  __shared__ unsigned short sB[3][64 * BK];   // 4 KB each (subtiled)

  const int tid = threadIdx.x;
  const int lane = tid & 63;
  const int wave = tid >> 6;
  const int wm = wave >> 1, wn = wave & 1;

  const int schunk = (lane & 3) ^ ((lane >> 3) & 3);
  const unsigned short* aSrc[2];
#pragma unroll
  for (int t4 = 0; t4 < 2; ++t4) {
    const int row = (t4 * 4 + wave) * 16 + (lane >> 2);
    aSrc[t4] = g + (size_t)(rowbase + row) * FD + schunk * 8;
  }

  const int kdec = wave * 8 + ((lane >> 5) << 2) + ((lane >> 1) & 3);
  const int ndec = ((lane >> 3) & 3) * 16 + (lane & 1) * 8;
  const float* bSrcF = w2 + ((size_t)e * FD + kdec) * HD + n0 + ndec;

  const int c = lane >> 4;
  int aoff[4];
#pragma unroll
  for (int m = 0; m < 4; ++m) {
    const int row = wm * 64 + m * 16 + (lane & 15);
    aoff[m] = row * 32 + ((c ^ ((row >> 1) & 3)) << 3);
  }
  const unsigned trlane = (lane & 15) * 8 + (lane >> 4) * 1024;
  unsigned trb[2];
#pragma unroll
  for (int n = 0; n < 2; ++n) trb[n] = trlane + (wn * 2 + n) * 128;
  const unsigned bbase = LDS_OFF(&sB[0][0]);

  const f32x4 zero = {0.f, 0.f, 0.f, 0.f};
  f32x4 acc[4][2];
#pragma unroll
  for (int m = 0; m < 4; ++m)
#pragma unroll
    for (int n = 0; n < 2; ++n) acc[m][n] = zero;

  float br0[8], br1[8];

#define FC2_BLOAD(KT, R) do {                                       \
    const float* _p = bSrcF + (size_t)(KT) * BK * HD;               \
    *(float4*)&R[0] = *(const float4*)_p;                           \
    *(float4*)&R[4] = *(const float4*)(_p + 4);                     \
  } while (0)

#define FC2_BWRITE(BUF, R) do {                                     \
    unsigned _a0,_a1,_a2,_a3;                                       \
    asm("v_cvt_pk_bf16_f32 %0, %1, %2" : "=v"(_a0) : "v"(R[0]), "v"(R[1])); \
    asm("v_cvt_pk_bf16_f32 %0, %1, %2" : "=v"(_a1) : "v"(R[2]), "v"(R[3])); \
    asm("v_cvt_pk_bf16_f32 %0, %1, %2" : "=v"(_a2) : "v"(R[4]), "v"(R[5])); \
    asm("v_cvt_pk_bf16_f32 %0, %1, %2" : "=v"(_a3) : "v"(R[6]), "v"(R[7])); \
    uint4 _u = make_uint4(_a0,_a1,_a2,_a3);                         \
    *(uint4*)&sB[BUF][wave * 512 + lane * 8] = _u;                  \
  } while (0)

#define FC2_ASTAGE(BUF, KT) do {                                    \
    for (int _t4 = 0; _t4 < 2; ++_t4)                               \
      GLL16(aSrc[_t4] + (size_t)(KT) * BK, &sA[BUF][(_t4 * 4 + wave) * 512]); \
  } while (0)

  const int NSTEP = FD / BK;   // 44
  // ---- prologue: lands steady queue [B1:2, A0:2, B2:2, A1:2] ----
  FC2_BLOAD(0, br0);
  __builtin_amdgcn_sched_barrier(0);
  asm volatile("s_waitcnt vmcnt(0)" ::: "memory");
  FC2_BWRITE(0, br0);
  __builtin_amdgcn_sched_barrier(0);
  FC2_BLOAD(1, br1);
  __builtin_amdgcn_sched_barrier(0);
  FC2_ASTAGE(0, 0);
  __builtin_amdgcn_sched_barrier(0);
  FC2_BLOAD(2, br0);
  __builtin_amdgcn_sched_barrier(0);
  FC2_ASTAGE(1, 1);
  __builtin_amdgcn_sched_barrier(0);
  asm volatile("s_waitcnt lgkmcnt(0)" ::: "memory");

#define FC2_STEP(T, R) do {                                                  \
    const int _t = (T);                                                      \
    if (_t < NSTEP - 2)      { asm volatile("s_waitcnt vmcnt(4)" ::: "memory"); } \
    else if (_t == NSTEP - 2){ asm volatile("s_waitcnt vmcnt(2)" ::: "memory"); } \
    else                     { asm volatile("s_waitcnt vmcnt(0)" ::: "memory"); } \
    __builtin_amdgcn_s_barrier();                                            \
    __builtin_amdgcn_sched_barrier(0);                                       \
    int _bnext = bsel + 1; if (_bnext >= 3) _bnext -= 3;                     \
    int _bn2 = bsel + 2; if (_bn2 >= 3) _bn2 -= 3;                           \
    if (_t + 1 < NSTEP) FC2_BWRITE(_bnext, R);                               \
    __builtin_amdgcn_sched_barrier(0);                                       \
    if (_t + 3 < NSTEP) FC2_BLOAD(_t + 3, R);                                \
    __builtin_amdgcn_sched_barrier(0);                                       \
    if (_t + 2 < NSTEP) FC2_ASTAGE(_bn2, _t + 2);                            \
    __builtin_amdgcn_sched_barrier(0);                                       \
    bf16x8 _af[4];                                                           \
    for (int _m = 0; _m < 4; ++_m)                                           \
      _af[_m] = *(const bf16x8*)&sA[bsel][aoff[_m]];                         \
    __builtin_amdgcn_sched_barrier(0);                                       \
    i32x2 _qlo[2], _qhi[2];                                                  \
    tr_issue(bbase + bsel * 4096 + trb[0], _qlo[0], _qhi[0]);                \
    __builtin_amdgcn_sched_barrier(0);                                       \
    tr_issue(bbase + bsel * 4096 + trb[1], _qlo[1], _qhi[1]);                \
    asm volatile("s_waitcnt lgkmcnt(2)" ::: "memory");                       \
    __builtin_amdgcn_sched_barrier(0);                                       \
    bf16x8 _bf0 = tr_pack(_qlo[0], _qhi[0]);                                 \
    __builtin_amdgcn_s_setprio(1);                                           \
    for (int _m = 0; _m < 4; ++_m)                                           \
      acc[_m][0] = __builtin_amdgcn_mfma_f32_16x16x32_bf16(_af[_m], _bf0, acc[_m][0], 0, 0, 0); \
    __builtin_amdgcn_s_setprio(0);                                           \
    asm volatile("s_waitcnt lgkmcnt(0)" ::: "memory");                       \
    __builtin_amdgcn_sched_barrier(0);                                       \
    bf16x8 _bf1 = tr_pack(_qlo[1], _qhi[1]);                                 \
    __builtin_amdgcn_s_setprio(1);                                           \
    for (int _m = 0; _m < 4; ++_m)                                           \
      acc[_m][1] = __builtin_amdgcn_mfma_f32_16x16x32_bf16(_af[_m], _bf1, acc[_m][1], 0, 0, 0); \
    __builtin_amdgcn_s_setprio(0);                                           \
  } while (0)

  int bsel = 0;
  for (int tt = 0; tt < NSTEP; tt += 2) {
    FC2_STEP(tt, br1);       // even t: bank1
    bsel = bsel + 1 == 3 ? 0 : bsel + 1;
    FC2_STEP(tt + 1, br0);   // odd t: bank0
    bsel = bsel + 1 == 3 ? 0 : bsel + 1;
  }

#pragma unroll
  for (int m = 0; m < 4; ++m) {
    const int rb = rowbase + wm * 64 + m * 16 + (lane >> 4) * 4;
#pragma unroll
    for (int n = 0; n < 2; ++n) {
      const int col = n0 + wn * 32 + n * 16 + (lane & 15);
#pragma unroll
      for (int r = 0; r < 4; ++r)
        o[(size_t)(rb + r) * OP + col] = acc[m][n][r];
    }
  }
}

// ---------------------------------------------------------------------------
// Combine (unchanged).
// ---------------------------------------------------------------------------
__global__ __launch_bounds__(256) void k_combine(
    const float* __restrict__ o, const int* __restrict__ tslot,
    float* __restrict__ out)
{
  const int t = blockIdx.x;
  const int c4 = threadIdx.x;
  const int sA = tslot[t * 2], sB = tslot[t * 2 + 1];
  const float4 a = reinterpret_cast<const float4*>(o + (size_t)sA * OP)[c4];
  const float4 b = reinterpret_cast<const float4*>(o + (size_t)sB * OP)[c4];
  float4 r;
  r.x = a.x + b.x; r.y = a.y + b.y; r.z = a.z + b.z; r.w = a.w + b.w;
  reinterpret_cast<float4*>(out)[(size_t)t * 256 + c4] = r;
}

// ---------------------------------------------------------------------------
extern "C" void kernel_launch(void* const* d_in, const int* in_sizes, int n_in,
                              void* d_out, int out_size, void* d_ws, size_t ws_size,
                              hipStream_t stream)
{
  const float* x  = (const float*)d_in[0];   // [2048,1,1024]
  const float* rw = (const float*)d_in[1];   // [1024,8]
  const float* w1 = (const float*)d_in[2];   // [8,1024,2816]
  const float* w2 = (const float*)d_in[3];   // [8,1408,1024]
  float* out = (float*)d_out;
  char* ws = (char*)d_ws;

  // ws layout (bytes)
  int*   ctrl   = (int*)(ws + 0);
  int*   tok_e  = (int*)(ws + 1024);
  float* tok_p  = (float*)(ws + 17408);
  int*   stok   = (int*)(ws + 33792);
  float* sp     = (float*)(ws + 54272);
  int*   tslot  = (int*)(ws + 74752);
  int*   widmt1 = (int*)(ws + 91136);
  int*   widmt2 = (int*)(ws + 94656);
  unsigned short* xbf = (unsigned short*)(ws + 97280);   // [T][HP]     4.33 MB
  unsigned short* g   = (unsigned short*)(ws + 4422656); // [SLOTS][F]  14.5 MB
  float*          o   = (float*)(ws + 18840576);         // [SLOTS][OP] 21.6 MB

  hipMemsetAsync(ws, 0, 1024, stream);

  k_router<<<T_TOK / 4, 256, 0, stream>>>(x, rw, xbf, ctrl, tok_e, tok_p);
  k_offsets<<<1, 256, 0, stream>>>(ctrl, tok_e, tok_p, stok, sp, tslot, widmt1, widmt2);
  k_fc1<<<FC1_NWG, 256, 0, stream>>>(xbf, w1, ctrl, stok, sp, widmt1, g);
  k_fc2<<<FC2_NWG, 256, 0, stream>>>(g, w2, ctrl, widmt2, o);
  k_combine<<<T_TOK, 256, 0, stream>>>(o, tslot, out);
}